// Round 9
// baseline (256.471 us; speedup 1.0000x reference)
//
#include <hip/hip_runtime.h>

// RNN: o_t = tanh(relu([x_t, o_{t-1}] @ W1[t] + b1[t]) @ W2[t] + b2[t]), T=30.
// Round-9 design (r8 recurrence + 2x block-level phase diversity):
//  - r8 post-mortem: dur 93.5, busy 67us (72% util), idle 26.5us ~= HBM time
//    (184MB ~30us) -> staging/gather phases are ADDITIVE, not overlapped:
//    only 5 phase-locked blocks/CU stage together (VALU idle), compute
//    together (HBM idle).
//  - Fix: halve the block. THR=128, EPB=128, ROW=129 (odd, bank-clean),
//    tile 31x129x4 = 15996B -> 16KB granule -> 10 blocks/CU x 2 waves
//    = same 20 waves/CU (LDS/elem is invariant ~124B so occupancy can't
//    rise) but 10 INDEPENDENTLY-phased blocks/CU: staging of some overlaps
//    t-loops of others; barriers span 2 waves (near-free). 16-workgroup
//    slot cap respected. Per-thread work identical to r8.
//  - Recurrence kept verbatim from r8 (measured at local floor: mov-free
//    5-op j-pairs, dual acc, xv prefetch, unroll 2). Micro: b2 folded as
//    scalar add into tanh arg instead of vector acc init (-1 mov/step).
//  - Weights: r7/r8 j-pair layout, 10.5KB K$-resident, s_load_dwordx*.

#define TS  30
#define HID 20
#define THR 128
#define EPB 128              // elements per block (M=1)
#define ROW 129              // LDS row stride in floats (odd -> bank-clean)
#define WST 44               // f2 slots per timestep in repacked weights

typedef float f2 __attribute__((ext_vector_type(2)));

__device__ __forceinline__ float fast_tanh(float y) {
    // tanh(y) = 1 - 2/(exp(2y)+1); correct saturation at +/-inf.
    float e = __expf(2.0f * y);
    return 1.0f - 2.0f * __builtin_amdgcn_rcpf(e + 1.0f);
}

// wp2[t*44 + s]: s in [0,10): {W1x[2s],W1x[2s+1]}
//               s in [10,20): {W1h[..]}   s in [20,30): {b1[..]}
//               s in [30,40): {W2[..]}    s == 40: {b2[t],0}; rest pad.
__global__ __launch_bounds__(256) void repack_w(
        const float* __restrict__ W1, const float* __restrict__ b1,
        const float* __restrict__ W2, const float* __restrict__ b2,
        f2* __restrict__ wp2) {
    for (int i = threadIdx.x; i < TS * WST; i += 256) {
        const int t = i / WST;
        const int s = i - t * WST;
        f2 v = {0.f, 0.f};
        if (s < 10) {
            const int j = 2 * s;
            v = (f2){W1[t * 40 + j], W1[t * 40 + j + 1]};
        } else if (s < 20) {
            const int j = 2 * (s - 10);
            v = (f2){W1[t * 40 + 20 + j], W1[t * 40 + 20 + j + 1]};
        } else if (s < 30) {
            const int j = 2 * (s - 20);
            v = (f2){b1[t * 20 + j], b1[t * 20 + j + 1]};
        } else if (s < 40) {
            const int j = 2 * (s - 30);
            v = (f2){W2[t * 20 + j], W2[t * 20 + j + 1]};
        } else if (s == 40) {
            v = (f2){b2[t], 0.f};
        }
        wp2[i] = v;
    }
}

__global__ __launch_bounds__(THR, 5) void rnn9(
        const float* __restrict__ x,
        const f2* __restrict__ wp2,
        float* __restrict__ out) {
    __shared__ float tile[(TS + 1) * ROW];           // +1 pad row (prefetch)
    const int tid = threadIdx.x;
    const size_t gbase = (size_t)blockIdx.x * (EPB * TS);

    // ---- coalesced float2 load + LDS transpose scatter ----
    const float2* xg = reinterpret_cast<const float2*>(x + gbase);
#pragma unroll
    for (int i = 0; i < 15; ++i) {
        const float2 v = xg[i * THR + tid];
        const unsigned f0 = (unsigned)(i * THR + tid) * 2u;
        const unsigned e0 = (f0 * 34953u) >> 20;     // exact f/30 for f < 74898
        const unsigned t0 = f0 - e0 * 30u;
        tile[t0 * ROW + e0] = v.x;
        const unsigned f1 = f0 + 1u;
        const unsigned e1 = (f1 * 34953u) >> 20;
        const unsigned t1 = f1 - e1 * 30u;
        tile[t1 * ROW + e1] = v.y;
    }
    __syncthreads();

    // ---- recurrence: M=1, j-pairs packed, xv prefetched, dual acc ----
    float o = 0.f;
    float xv = tile[tid];                            // prefetch t=0
#pragma unroll 2
    for (int t = 0; t < TS; ++t) {
        const f2* wr = wp2 + t * WST;                // wave-uniform -> s_load
        const float xv_n = tile[(t + 1) * ROW + tid];  // prefetch t+1 (pad ok)
        const float b2v = wr[40].x;
        const f2 x2 = {xv, xv};
        const f2 o2 = {o, o};
        f2 acc0 = {0.f, 0.f};
        f2 acc1 = {0.f, 0.f};
#pragma unroll
        for (int jj = 0; jj < 10; jj += 2) {
            {                                        // even jj -> acc0
                f2 p = x2 * wr[jj];                  // pk_mul   (1 SGPR)
                p = o2 * wr[10 + jj] + p;            // pk_fma   (1 SGPR)
                p = p + wr[20 + jj];                 // pk_add   (1 SGPR)
                p.x = __builtin_fmaxf(p.x, 0.f);
                p.y = __builtin_fmaxf(p.y, 0.f);     // pk_max
                acc0 = p * wr[30 + jj] + acc0;       // pk_fma   (1 SGPR)
            }
            {                                        // odd jj -> acc1
                f2 p = x2 * wr[jj + 1];
                p = o2 * wr[10 + jj + 1] + p;
                p = p + wr[20 + jj + 1];
                p.x = __builtin_fmaxf(p.x, 0.f);
                p.y = __builtin_fmaxf(p.y, 0.f);
                acc1 = p * wr[30 + jj + 1] + acc1;
            }
        }
        const f2 acc = acc0 + acc1;                  // pk_add
        o = fast_tanh(acc.x + acc.y + b2v);
        tile[t * ROW + tid] = o;                     // in-place: x -> o
        xv = xv_n;
    }
    __syncthreads();

    // ---- LDS gather + coalesced float2 store ----
    float2* og = reinterpret_cast<float2*>(out + gbase);
#pragma unroll
    for (int i = 0; i < 15; ++i) {
        const unsigned f0 = (unsigned)(i * THR + tid) * 2u;
        const unsigned e0 = (f0 * 34953u) >> 20;
        const unsigned t0 = f0 - e0 * 30u;
        const unsigned f1 = f0 + 1u;
        const unsigned e1 = (f1 * 34953u) >> 20;
        const unsigned t1 = f1 - e1 * 30u;
        float2 v;
        v.x = tile[t0 * ROW + e0];
        v.y = tile[t1 * ROW + e1];
        og[i * THR + tid] = v;
    }
}

extern "C" void kernel_launch(void* const* d_in, const int* in_sizes, int n_in,
                              void* d_out, int out_size, void* d_ws, size_t ws_size,
                              hipStream_t stream) {
    const float* x  = (const float*)d_in[0];
    const float* W1 = (const float*)d_in[1];
    const float* b1 = (const float*)d_in[2];
    const float* W2 = (const float*)d_in[3];
    const float* b2 = (const float*)d_in[4];
    float* out = (float*)d_out;
    f2* wp2 = (f2*)d_ws;                             // 30*44*8 = 10560 B

    repack_w<<<1, 256, 0, stream>>>(W1, b1, W2, b2, wp2);

    const int B = 1048576;
    const int grid = B / EPB;                        // 8192 blocks
    rnn9<<<grid, THR, 0, stream>>>(x, wp2, out);
}